// Round 3
// baseline (232.489 us; speedup 1.0000x reference)
//
#include <hip/hip_runtime.h>
#include <hip/hip_fp16.h>
#include <stdint.h>

typedef float floatx4 __attribute__((ext_vector_type(4)));
typedef short short8 __attribute__((ext_vector_type(8)));

constexpr int I_SZ = 256, O_SZ = 256, NCOL = 512, B_SZ = 4096;
constexpr int KSTEPS = 264;           // 256 RBF steps + 8 silu steps
constexpr float GSTEP = 4.0f / 7.0f;  // linspace(-2,2,8) step
constexpr float NLOG2E = -1.44269504088896f;

// pack two fp32 -> two bf16 (truncate) in one v_perm_b32
__device__ __forceinline__ uint32_t pk_bf16(float lo, float hi) {
  return __builtin_amdgcn_perm(__float_as_uint(hi), __float_as_uint(lo), 0x07060302u);
}
__device__ __forceinline__ short rne_bf16(float f) {
  uint32_t u = __float_as_uint(f);
  return (short)((u + 0x7FFFu + ((u >> 16) & 1u)) >> 16);
}

__device__ __forceinline__ void gload_lds16(const void* g, void* l) {
  __builtin_amdgcn_global_load_lds((const __attribute__((address_space(1))) void*)g,
                                   (__attribute__((address_space(3))) void*)l,
                                   16, 0, 0);
}

__device__ __forceinline__ float silu_f(float a) {
  return a * __builtin_amdgcn_rcpf(1.f + __builtin_amdgcn_exp2f(a * NLOG2E));
}

// ---------------- weight packing: K-major Wpack[s][ph][slot][n][e] bf16 ----------------
// k = ph*32 + slot*8 + e ; n = 2*o + c. Contiguous in n -> gload_lds staging is linear.
__global__ void pack_weights(const float* __restrict__ rw, const float* __restrict__ cw,
                             const float* __restrict__ swre, const float* __restrict__ swim,
                             short* __restrict__ wpack) {
  int idx = blockIdx.x * 256 + threadIdx.x;   // (s, ph, slot, n): 264*2*4*512 groups of 8
  int n = idx & 511;
  int slot = (idx >> 9) & 3;
  int ph = (idx >> 11) & 1;
  int s = idx >> 12;
  int u = ph * 4 + slot;                      // k-group: k = u*8 + e
  int o = n >> 1, c = n & 1;
  float w[8];
  if (s < 256) {
    const float* W = (c ? cw : rw) + (((size_t)s * O_SZ + o) << 6) + (u << 3);
    float4 a = *(const float4*)W;
    float4 b = *(const float4*)(W + 4);
    w[0] = a.x; w[1] = a.y; w[2] = a.z; w[3] = a.w;
    w[4] = b.x; w[5] = b.y; w[6] = b.z; w[7] = b.w;
  } else {
    int kp0 = ((s - 256) << 6) + (u << 3);
    #pragma unroll
    for (int e = 0; e < 8; ++e) {
      int kp = kp0 + e, i = kp >> 1, ci = kp & 1;
      float a = swre[i * O_SZ + o], b = swim[i * O_SZ + o];
      w[e] = (c == 0) ? (ci == 0 ? a : -b) : (ci == 0 ? b : a);
    }
  }
  uint32_t h[8];
  #pragma unroll
  for (int e = 0; e < 8; ++e) h[e] = (uint32_t)(uint16_t)rne_bf16(w[e]);
  uint4 val = make_uint4(h[0] | (h[1] << 16), h[2] | (h[3] << 16),
                         h[4] | (h[5] << 16), h[6] | (h[7] << 16));
  *(uint4*)(wpack + (size_t)idx * 8) = val;
}

// ---------------- x transpose: xT[c][i][b] fp16 from x[b][i] fp32 ----------------
__global__ void transpose_x(const float* __restrict__ xre, const float* __restrict__ xim,
                            __half* __restrict__ xT) {
  __shared__ float tile[64][65];
  int bt = blockIdx.x & 63;           // b-tile (4096/64)
  int it = (blockIdx.x >> 6) & 3;     // i-tile (256/64)
  int c  = blockIdx.x >> 8;           // plane
  const float* src = (c ? xim : xre);
  int b0 = bt << 6, i0 = it << 6;
  int t = threadIdx.x;
  int il = t & 63, bh = t >> 6;
  #pragma unroll
  for (int k = 0; k < 16; ++k) {
    int bl = bh + (k << 2);
    tile[bl][il] = src[(size_t)(b0 + bl) * I_SZ + i0 + il];
  }
  __syncthreads();
  int bl2 = t & 63, ih = t >> 6;
  __half* dst = xT + ((size_t)c * I_SZ + i0) * B_SZ + b0;
  #pragma unroll
  for (int k = 0; k < 16; ++k) {
    int il2 = ih + (k << 2);
    dst[(size_t)il2 * B_SZ + bl2] = __float2half(tile[bl2][il2]);
  }
}

// ---------------- bias column sums ----------------
__global__ void bias_sums(const float* __restrict__ bre, const float* __restrict__ bim,
                          float* __restrict__ bsum) {
  int n = blockIdx.x, o = n >> 1, l = threadIdx.x;
  const float* src = ((n & 1) ? bim : bre) + o;
  float s = 0.f;
  #pragma unroll
  for (int a = 0; a < 4; ++a) s += src[(size_t)(a * 64 + l) * O_SZ];
  #pragma unroll
  for (int off = 32; off; off >>= 1) s += __shfl_down(s, off, 64);
  if (l == 0) bsum[n] = s;
}

// ---------------- main fused GEMM ----------------
// block: 128 rows x 256 cols, 8 waves (2x4 of 64x64), split-K = 8 chunks (XCD-aligned).
// 66 micro-steps of K=32 (33 steps x 2 halves). K-major LDS (no swizzle, conflict-free).
// B double-buffered with counted vmcnt(2) (prefetch stays in flight across the barrier);
// A built into ONE uint4/thread during the MFMA phase, published next iter (1 ds_write).
// Geometry keeps total regs <= 128/thread (64 AGPR acc + ~56 VGPR) -> 2 blocks/CU exact.
__global__ __launch_bounds__(512, 4) void cvkan_gemm(
    const float* __restrict__ xre, const float* __restrict__ xim,
    const __half* __restrict__ xT,
    const short* __restrict__ wpack, const float* __restrict__ bsum,
    float* __restrict__ out) {
  __shared__ __align__(16) short As[4 * 128 * 8];        // [slot][row][8]  (8 KB)
  __shared__ __align__(16) short Bs[2][4 * 256 * 8];     // dbuf [slot][col][8] (2x16 KB)

  const int tid = threadIdx.x;
  const int bid = blockIdx.x;
  const int kch = bid & 7;              // XCD-aligned: each XCD keeps one ~2MB wpack slice in L2
  const int mn = bid >> 3;              // 0..63
  const int mt = mn >> 1, nt = mn & 1;
  const int b0 = mt * 128, n0 = nt * 256;
  const int l = tid & 63, w = tid >> 6;
  const int wr = w >> 2, wc = w & 3;    // 2x4 wave grid, each wave 64x64
  const int lm = l & 15, q = l >> 4;
  const int ar = tid & 127, au = tid >> 7;   // A-build: row ar (consecutive lanes), u-slot au

  const __half* xTre = xT;
  const __half* xTim = xT + (size_t)I_SZ * B_SZ;

  floatx4 acc[4][4] = {};
  uint4 rA;            // A fragment for current micro-step (built during previous MFMA phase)
  float eiv[8];        // exp(-(xi-v)^2) cache for current s (shared across both halves)
  float xr_s;          // xr for current s (ph1's er needs it)

  // micro-step t: js = t>>1, ph = t&1 ; s = js<32 ? kch*32+js : 256+kch (silu)
  auto stage_B = [&](short* bdst, int t) {
    int js = t >> 1, ph = t & 1;
    int s = (js < 32) ? (kch * 32 + js) : (256 + kch);
    const short* src = wpack + (size_t)(s * 2 + ph) * 16384 + ((tid >> 8) << 12)
                       + (n0 << 3) + ((tid & 255) << 3);
    short* ldst = bdst + (w << 9);      // LDS dest linear in tid (wave base + lane*16B)
    gload_lds16(src,        ldst);
    gload_lds16(src + 8192, ldst + 4096);
  };

  auto build_rbf = [&](int u, float xr) {   // er(u) * eiv[0..7] -> rA
    float d = xr - (-2.0f + u * GSTEP);
    float er = __builtin_amdgcn_exp2f(d * d * NLOG2E);
    rA = make_uint4(pk_bf16(er * eiv[0], er * eiv[1]), pk_bf16(er * eiv[2], er * eiv[3]),
                    pk_bf16(er * eiv[4], er * eiv[5]), pk_bf16(er * eiv[6], er * eiv[7]));
  };

  auto build_silu = [&](int s, int u) {     // silu step: k=2i+c interleave
    int sl = s - 256;
    const float* pr = xre + (size_t)(b0 + ar) * I_SZ + (sl << 5) + (u << 2);
    const float* pi = xim + (size_t)(b0 + ar) * I_SZ + (sl << 5) + (u << 2);
    rA = make_uint4(pk_bf16(silu_f(pr[0]), silu_f(pi[0])),
                    pk_bf16(silu_f(pr[1]), silu_f(pi[1])),
                    pk_bf16(silu_f(pr[2]), silu_f(pi[2])),
                    pk_bf16(silu_f(pr[3]), silu_f(pi[3])));
  };

  // ---- prologue: stage B(t=0); build eiv + rA(t=0) ----
  stage_B(&Bs[0][0], 0);
  {
    int s0 = kch * 32;
    float xi0 = __half2float(xTim[(size_t)s0 * B_SZ + b0 + ar]);
    xr_s = __half2float(xTre[(size_t)s0 * B_SZ + b0 + ar]);
    #pragma unroll
    for (int v = 0; v < 8; ++v) {
      float d = xi0 - (-2.0f + v * GSTEP);
      eiv[v] = __builtin_amdgcn_exp2f(d * d * NLOG2E);
    }
    build_rbf(au, xr_s);
  }

  short* bc = &Bs[0][0];
  short* bn = &Bs[1][0];
  float xr_n = 0.f, xi_n = 0.f;

  for (int t = 0; t < 66; ++t) {
    // prefetch next-s x while older than the stage (drained harmlessly by this iter's wait)
    if (t < 65 && (t & 1) == 1) {
      int jsn = (t + 1) >> 1;
      if (jsn < 32) {
        int sn = kch * 32 + jsn;
        xr_n = __half2float(xTre[(size_t)sn * B_SZ + b0 + ar]);
        xi_n = __half2float(xTim[(size_t)sn * B_SZ + b0 + ar]);
      }
    }
    __builtin_amdgcn_sched_barrier(0);

    if (t < 65) stage_B(bn, t + 1);     // prefetch next half-tile (in flight across barrier)
    *(uint4*)(As + (au << 10) + (ar << 3)) = rA;   // publish A(t): 1 ds_write_b128

    // drain stage(t) (issued last iter), keep stage(t+1) in flight; publish A ds_write
    if (t < 65) asm volatile("s_waitcnt vmcnt(2) lgkmcnt(0)" ::: "memory");
    else        asm volatile("s_waitcnt vmcnt(0) lgkmcnt(0)" ::: "memory");
    __builtin_amdgcn_s_barrier();

    // build rA(t+1) in regs — overlaps the MFMA cluster below (VALU || MFMA pipes)
    if (t < 65) {
      int tn = t + 1, jsn = tn >> 1, phn = tn & 1;
      int sn = (jsn < 32) ? (kch * 32 + jsn) : (256 + kch);
      if (sn >= 256) {
        build_silu(sn, phn * 4 + au);
      } else if (phn == 0) {            // new s: fresh eiv from prefetched x
        xr_s = xr_n;
        #pragma unroll
        for (int v = 0; v < 8; ++v) {
          float d = xi_n - (-2.0f + v * GSTEP);
          eiv[v] = __builtin_amdgcn_exp2f(d * d * NLOG2E);
        }
        build_rbf(au, xr_s);
      } else {                          // second half of same s: cached eiv
        build_rbf(4 + au, xr_s);
      }
    }

    // --- fragments (K-major, contiguous per 16-lane group: conflict-free) + MFMA ---
    short8 bf[4];
    #pragma unroll
    for (int nn = 0; nn < 4; ++nn)
      bf[nn] = *(const short8*)(bc + (q << 11) + ((wc * 64 + nn * 16 + lm) << 3));
    __builtin_amdgcn_s_setprio(1);
    #pragma unroll
    for (int mm = 0; mm < 4; ++mm) {
      short8 a = *(const short8*)(As + (q << 10) + ((wr * 64 + mm * 16 + lm) << 3));
      #pragma unroll
      for (int nn = 0; nn < 4; ++nn)
        acc[mm][nn] = __builtin_amdgcn_mfma_f32_16x16x32_bf16(a, bf[nn], acc[mm][nn], 0, 0, 0);
    }
    __builtin_amdgcn_s_setprio(0);

    if (t < 65) __builtin_amdgcn_s_barrier();   // A reads done before next iter's write/stage
    short* tmp = bc; bc = bn; bn = tmp;
  }

  // --- epilogue: C/D layout col=lane&15, row=q*4+reg; bias added by chunk-7 only ---
  #pragma unroll
  for (int nn = 0; nn < 4; ++nn) {
    int col = n0 + wc * 64 + nn * 16 + lm;
    float bv = (kch == 7) ? bsum[col] : 0.0f;
    #pragma unroll
    for (int mm = 0; mm < 4; ++mm) {
      int row0 = b0 + wr * 64 + mm * 16 + (q << 2);
      #pragma unroll
      for (int r2 = 0; r2 < 4; ++r2)
        atomicAdd(out + (size_t)(row0 + r2) * NCOL + col, acc[mm][nn][r2] + bv);
    }
  }
}

extern "C" void kernel_launch(void* const* d_in, const int* in_sizes, int n_in,
                              void* d_out, int out_size, void* d_ws, size_t ws_size,
                              hipStream_t stream) {
  const float* xre  = (const float*)d_in[0];
  const float* xim  = (const float*)d_in[1];
  const float* rw   = (const float*)d_in[2];
  const float* cw   = (const float*)d_in[3];
  const float* swre = (const float*)d_in[4];
  const float* swim = (const float*)d_in[5];
  const float* bre  = (const float*)d_in[6];
  const float* bim  = (const float*)d_in[7];
  float* out = (float*)d_out;

  size_t wpack_bytes = (size_t)KSTEPS * NCOL * 64 * 2;   // 16.5 MiB
  short* wpack = (short*)d_ws;
  float* bsum  = (float*)((char*)d_ws + wpack_bytes);
  __half* xT   = (__half*)((char*)d_ws + wpack_bytes + 2048);  // 2 planes * 256*4096 fp16

  hipMemsetAsync(d_out, 0, (size_t)B_SZ * NCOL * sizeof(float), stream);
  pack_weights<<<(KSTEPS * NCOL * 8) / 256, 256, 0, stream>>>(rw, cw, swre, swim, wpack);
  transpose_x<<<512, 256, 0, stream>>>(xre, xim, xT);
  bias_sums<<<NCOL, 64, 0, stream>>>(bre, bim, bsum);
  cvkan_gemm<<<512, 512, 0, stream>>>(xre, xim, xT, wpack, bsum, out);
}